// Round 1
// baseline (720.954 us; speedup 1.0000x reference)
//
#include <hip/hip_runtime.h>

// Problem constants (reference: B=64, T=2048, D=512, H=64, K=3, S=3, PAD=1)
#define T_LEN 2048
#define D_DIM 512
#define B_SZ  64
#define C1    128        // 2*H conv1 output channels
#define T1_LEN 683       // conv1 output length: ceil(2048/3)
#define T2_LEN 228       // conv2 output length: ceil(683/3)
#define NSEL  32         // B * BATCH_FACTOR

// Workspace layout (bytes)
constexpr size_t OFF_WPACK = 0;                                   // 128*512*3 floats = 786432 B
constexpr size_t OFF_HM    = 786432;                              // 64*64*683 floats = 11186176 B
constexpr size_t OFF_EST   = OFF_HM + (size_t)B_SZ*64*T1_LEN*4;   // 64 floats
constexpr size_t OFF_SEL   = OFF_EST + 256;                       // 32 ints

// ---------------------------------------------------------------------------
// Kernel 0: repack w1 (c,d,k) -> wpack[(k*512+d)*128 + c] so conv1 A-tile
// loads are fully coalesced.
__global__ __launch_bounds__(256) void pack_w1(const float* __restrict__ w1,
                                               float* __restrict__ wpack) {
    int idx = blockIdx.x * 256 + threadIdx.x;      // < 196608 exactly (768 blocks)
    int c = idx & 127;
    int r = idx >> 7;          // k*512 + d
    int d = r & 511;
    int k = r >> 9;
    wpack[idx] = w1[c * 1536 + d * 3 + k];
}

// ---------------------------------------------------------------------------
// Kernel 1: conv1 (stride 3, pad 1) + channel-pair maxpool, as a tiled GEMM.
// Per block: one batch b, a 128-wide t1 tile, all 128 channels.
// K dim = (k outer, d inner) = 1536, chunked by 16.
// h[b,c,t1] = b1[c] + sum_{k,d} w1[c,d,k] * x[b, 3*t1+k-1, d]
// hm[b,j,t1] = max(h[b,2j,t1], h[b,2j+1,t1])
__global__ __launch_bounds__(256) void conv1_pool(const float* __restrict__ x,
                                                  const float* __restrict__ wpack,
                                                  const float* __restrict__ b1,
                                                  float* __restrict__ hm) {
    __shared__ __align__(16) float As[16 * 128];   // [kk][c]
    __shared__ __align__(16) float Bs[16 * 132];   // [kk][t1], stride 132 for alignment

    const int b     = blockIdx.y;
    const int t1g0  = blockIdx.x * 128;
    const int tid   = threadIdx.x;
    const int c0    = (tid & 15) * 8;    // 8 consecutive channels (aligned pairs)
    const int t0    = (tid >> 4) * 8;    // 8 consecutive t1

    float acc[8][8];
    #pragma unroll
    for (int i = 0; i < 8; ++i)
        #pragma unroll
        for (int j = 0; j < 8; ++j) acc[i][j] = 0.f;

    const float* xb = x + (size_t)b * T_LEN * D_DIM;

    // B-tile load role: thread -> (t1 = tid&127, kk-group = tid>>7)
    const int lt1  = tid & 127;
    const int kkg  = tid >> 7;                   // 0..1
    const int pbase = 3 * (t1g0 + lt1) - 1;      // input position for k=0

    for (int kc = 0; kc < 96; ++kc) {
        const int k  = kc >> 5;
        const int d0 = (kc & 31) << 4;

        // --- stage A tile (16 kk x 128 c), fully coalesced from wpack
        {
            const float4* src = (const float4*)(wpack + ((size_t)(k * 512 + d0) << 7));
            float4 a0 = src[tid * 2];
            float4 a1 = src[tid * 2 + 1];
            ((float4*)As)[tid * 2]     = a0;
            ((float4*)As)[tid * 2 + 1] = a1;
        }
        // --- stage B tile: Bs[kk][t1] = x[b, 3*t1+k-1, d0+kk]; zero when p OOB
        {
            const int p = pbase + k;
            const bool inb = (unsigned)p < (unsigned)T_LEN;   // covers t1 >= 683 too
            const float* xrow = xb + (size_t)(inb ? p : 0) * D_DIM + d0;
            #pragma unroll
            for (int q = 0; q < 2; ++q) {
                const int kk0 = (kkg + 2 * q) * 4;
                float4 v = make_float4(0.f, 0.f, 0.f, 0.f);
                if (inb) v = *(const float4*)(xrow + kk0);
                Bs[(kk0 + 0) * 132 + lt1] = v.x;
                Bs[(kk0 + 1) * 132 + lt1] = v.y;
                Bs[(kk0 + 2) * 132 + lt1] = v.z;
                Bs[(kk0 + 3) * 132 + lt1] = v.w;
            }
        }
        __syncthreads();

        #pragma unroll
        for (int kk = 0; kk < 16; ++kk) {
            const float4 a0 = *(const float4*)&As[kk * 128 + c0];
            const float4 a1 = *(const float4*)&As[kk * 128 + c0 + 4];
            const float4 q0 = *(const float4*)&Bs[kk * 132 + t0];
            const float4 q1 = *(const float4*)&Bs[kk * 132 + t0 + 4];
            const float av[8] = {a0.x, a0.y, a0.z, a0.w, a1.x, a1.y, a1.z, a1.w};
            const float bv[8] = {q0.x, q0.y, q0.z, q0.w, q1.x, q1.y, q1.z, q1.w};
            #pragma unroll
            for (int i = 0; i < 8; ++i)
                #pragma unroll
                for (int j = 0; j < 8; ++j)
                    acc[i][j] = fmaf(av[i], bv[j], acc[i][j]);
        }
        __syncthreads();
    }

    // Epilogue: +bias, maxpool channel pairs (c0 is 8-aligned -> 4 whole pairs)
    float* hmb = hm + (size_t)b * 64 * T1_LEN;
    #pragma unroll
    for (int i = 0; i < 4; ++i) {
        const int c  = c0 + 2 * i;
        const int j  = c >> 1;
        const float bia0 = b1[c];
        const float bia1 = b1[c + 1];
        #pragma unroll
        for (int t = 0; t < 8; ++t) {
            const int t1 = t1g0 + t0 + t;
            if (t1 < T1_LEN) {
                const float v0 = acc[2 * i][t]     + bia0;
                const float v1 = acc[2 * i + 1][t] + bia1;
                hmb[(size_t)j * T1_LEN + t1] = fmaxf(v0, v1);
            }
        }
    }
}

// ---------------------------------------------------------------------------
// Kernel 2: conv2 (64ch->1, stride 3, pad 1) + per-batch sum -> est[b]
__global__ __launch_bounds__(256) void conv2_est(const float* __restrict__ hm,
                                                 const float* __restrict__ w2,
                                                 const float* __restrict__ b2,
                                                 const int* __restrict__ seq_lens,
                                                 float* __restrict__ est) {
    const int b  = blockIdx.x;
    const int t2 = threadIdx.x;
    __shared__ float sw2[192];
    if (threadIdx.x < 192) sw2[threadIdx.x] = w2[threadIdx.x];
    __syncthreads();

    float s = 0.f;
    if (t2 < T2_LEN) {
        const float* hmb = hm + (size_t)b * 64 * T1_LEN;
        const int t1b = 3 * t2 - 1;
        for (int j = 0; j < 64; ++j) {
            const float* row = hmb + (size_t)j * T1_LEN;
            #pragma unroll
            for (int k = 0; k < 3; ++k) {
                const int t1 = t1b + k;
                if ((unsigned)t1 < (unsigned)T1_LEN)
                    s = fmaf(row[t1], sw2[j * 3 + k], s);
            }
        }
        s += b2[0];
    }

    __shared__ float red[256];
    red[threadIdx.x] = s;
    __syncthreads();
    for (int off = 128; off > 0; off >>= 1) {
        if (threadIdx.x < off) red[threadIdx.x] += red[threadIdx.x + off];
        __syncthreads();
    }
    if (threadIdx.x == 0) {
        const int L   = seq_lens[b];
        const int sl1 = (L + 2) / 3;          // ceil(L/3)
        const int sl  = (sl1 + 2) / 3;        // ceil(sl1/3)
        const float mean = red[0] / 228.0f;
        est[b] = mean * (228.0f / (float)sl);
    }
}

// ---------------------------------------------------------------------------
// Kernel 3: top-32 of 64 (ties -> lower index, matching jax.lax.top_k),
// indices compacted in ascending order; writes sel idx + sel_lens (as float).
__global__ void select_k(const float* __restrict__ est,
                         const int* __restrict__ seq_lens,
                         int* __restrict__ sel,
                         float* __restrict__ out_lens) {
    const int i = threadIdx.x;  // 64 threads = 1 wave
    __shared__ float e[64];
    e[i] = est[i];
    __syncthreads();
    const float ei = e[i];
    int rank = 0;
    for (int j = 0; j < 64; ++j) {
        const float ej = e[j];
        rank += (ej > ei) || (ej == ei && j < i);
    }
    const bool selected = rank < NSEL;
    const unsigned long long mask = __ballot(selected);
    if (selected) {
        const int pos = __popcll(mask & ((1ull << i) - 1ull));
        sel[pos] = i;
        out_lens[pos] = (float)seq_lens[i];
    }
}

// ---------------------------------------------------------------------------
// Kernel 4: gather selected rows, float4-vectorized.
__global__ __launch_bounds__(256) void gather_rows(const float* __restrict__ x,
                                                   const int* __restrict__ sel,
                                                   float* __restrict__ out,
                                                   int n4row) {
    const int i = blockIdx.y;
    const int v = blockIdx.x * 256 + threadIdx.x;
    if (v < n4row) {
        const int src = sel[i];
        const float4* xs = (const float4*)(x + (size_t)src * T_LEN * D_DIM);
        float4* od = (float4*)(out + (size_t)i * ((size_t)n4row * 4));
        od[v] = xs[v];
    }
}

// ---------------------------------------------------------------------------
extern "C" void kernel_launch(void* const* d_in, const int* in_sizes, int n_in,
                              void* d_out, int out_size, void* d_ws, size_t ws_size,
                              hipStream_t stream) {
    const float* x        = (const float*)d_in[0];
    const int*   seq_lens = (const int*)  d_in[1];
    const float* w1       = (const float*)d_in[2];
    const float* b1       = (const float*)d_in[3];
    const float* w2       = (const float*)d_in[4];
    const float* b2       = (const float*)d_in[5];
    float* out = (float*)d_out;

    char* ws = (char*)d_ws;
    float* wpack = (float*)(ws + OFF_WPACK);
    float* hm    = (float*)(ws + OFF_HM);
    float* est   = (float*)(ws + OFF_EST);
    int*   sel   = (int*)  (ws + OFF_SEL);

    // out_size = NSEL*max_time*512 + NSEL  ->  recover max_time on host
    const int max_time = (out_size - NSEL) / (NSEL * D_DIM);

    pack_w1<<<768, 256, 0, stream>>>(w1, wpack);
    conv1_pool<<<dim3(6, B_SZ), 256, 0, stream>>>(x, wpack, b1, hm);
    conv2_est<<<B_SZ, 256, 0, stream>>>(hm, w2, b2, seq_lens, est);
    select_k<<<1, 64, 0, stream>>>(est, seq_lens, sel,
                                   out + (size_t)NSEL * max_time * D_DIM);
    const int n4row = max_time * (D_DIM / 4);
    gather_rows<<<dim3((n4row + 255) / 256, NSEL), 256, 0, stream>>>(x, sel, out, n4row);
}

// Round 2
// 460.086 us; speedup vs baseline: 1.5670x; 1.5670x over previous
//
#include <hip/hip_runtime.h>

// Problem: B=64, T=2048, D=512, H=64, K=3, S=3, PAD=1
#define T_LEN 2048
#define D_DIM 512
#define B_SZ  64
#define T1_LEN 683     // ceil(2048/3)
#define NSEL  32
#define KTOT  1536     // 3*512 reduction dim of conv1-as-GEMM
#define BK    64       // K chunk per iteration
#define TILE_T1 96     // t1 tile per block; 8 tiles cover 768 >= 683
#define NTILES 8

typedef __attribute__((ext_vector_type(8))) short bf16x8;
typedef __attribute__((ext_vector_type(4))) float f32x4;

// Workspace layout (bytes)
constexpr size_t OFF_WHI = 0;         // 128*1536 bf16 = 393216 B
constexpr size_t OFF_WLO = 393216;    // 393216 B
constexpr size_t OFF_EST = 786432;    // 64 floats
constexpr size_t OFF_SEL = 786944;    // 32 ints

__device__ inline unsigned bf16_rne(float x) {
    unsigned u = __float_as_uint(x);
    return (u + 0x7FFFu + ((u >> 16) & 1u)) >> 16;
}

// ---------------------------------------------------------------------------
// Pack w1[c][d][k] -> whi/wlo[c][kappa = k*512 + d] (bf16 hi/lo split).
// Also zeroes est_raw (runs before conv1 in stream order every launch).
__global__ __launch_bounds__(256) void pack_w1_split(const float* __restrict__ w1,
                                                     unsigned short* __restrict__ whi,
                                                     unsigned short* __restrict__ wlo,
                                                     float* __restrict__ est_raw) {
    if (blockIdx.x == 0 && threadIdx.x < 64) est_raw[threadIdx.x] = 0.f;
    int idx = blockIdx.x * 256 + threadIdx.x;   // 768 blocks * 256 = 196608 exact
    int c = idx / 1536;
    int kap = idx - c * 1536;
    int k = kap >> 9, d = kap & 511;
    float v = w1[c * 1536 + d * 3 + k];
    unsigned hb = bf16_rne(v);
    float hf = __uint_as_float(hb << 16);
    whi[idx] = (unsigned short)hb;
    wlo[idx] = (unsigned short)bf16_rne(v - hf);
}

// ---------------------------------------------------------------------------
// conv1 (GEMM via 3-term split-bf16 MFMA) + bias + pair-maxpool + mod-3
// weighted reduction -> atomicAdd(est_raw[b]).
// Block: batch b, 96-wide t1 tile, all 128 channels. 4 waves, each owns a
// 64c x 48t1 quadrant = 4x3 frags of 16x16 (MFMA 16x16x32 bf16).
// LDS tiles stored [row][k-chunk-of-8, XOR-swizzled by row&7].
__global__ __launch_bounds__(256, 2) void conv1_mfma(
        const float* __restrict__ x,
        const unsigned short* __restrict__ whi,
        const unsigned short* __restrict__ wlo,
        const float* __restrict__ b1,
        const float* __restrict__ w2,
        float* __restrict__ est_raw) {
    __shared__ __align__(16) unsigned short Ahi[128 * 64];  // 16 KB
    __shared__ __align__(16) unsigned short Alo[128 * 64];
    __shared__ __align__(16) unsigned short Bhi[96 * 64];   // 12 KB
    __shared__ __align__(16) unsigned short Blo[96 * 64];
    __shared__ float b1s[128];
    __shared__ float w2s[192];
    __shared__ float red[256];

    const int tid  = threadIdx.x;
    const int lane = tid & 63;
    const int w    = tid >> 6;
    const int b    = blockIdx.y;
    const int t1g0 = blockIdx.x * TILE_T1;

    if (tid < 128) b1s[tid] = b1[tid];
    if (tid < 192) w2s[tid] = w2[tid];

    const float* xb = x + (size_t)b * (T_LEN * (size_t)D_DIM);

    const int l15  = lane & 15;
    const int quad = lane >> 4;
    const int c0w  = (w >> 1) * 64;   // c quadrant
    const int t0w  = (w & 1) * 48;    // t1 quadrant

    int offA[4], swA[4];
    #pragma unroll
    for (int mi = 0; mi < 4; ++mi) { int r = c0w + mi * 16 + l15; offA[mi] = r * 64; swA[mi] = r & 7; }
    int offB[3], swB[3];
    #pragma unroll
    for (int ni = 0; ni < 3; ++ni) { int r = t0w + ni * 16 + l15; offB[ni] = r * 64; swB[ni] = r & 7; }

    f32x4 acc[4][3];
    #pragma unroll
    for (int mi = 0; mi < 4; ++mi)
        #pragma unroll
        for (int ni = 0; ni < 3; ++ni) acc[mi][ni] = (f32x4){0.f, 0.f, 0.f, 0.f};

    for (int k0 = 0; k0 < KTOT; k0 += BK) {
        // ---- stage A tile: 128 rows x 8 chunks (hi+lo), 4 chunk-ids/thread
        #pragma unroll
        for (int q = 0; q < 4; ++q) {
            int id = tid + 256 * q;               // 0..1023
            int row = id >> 3, c8 = id & 7;
            const size_t src = (size_t)row * 1536 + k0 + c8 * 8;
            int4 vh = *(const int4*)(whi + src);
            int4 vl = *(const int4*)(wlo + src);
            int dst = row * 64 + ((c8 ^ (row & 7)) << 3);
            *(int4*)(Ahi + dst) = vh;
            *(int4*)(Alo + dst) = vl;
        }
        // ---- stage B tile: 96 rows x 8 chunks, fp32 load + split, 3 ids/thread
        #pragma unroll
        for (int q = 0; q < 3; ++q) {
            int id = tid + 256 * q;               // 0..767
            int row = id >> 3, c8 = id & 7;
            int t1abs = t1g0 + row;
            long g = 1536L * t1abs + (k0 + c8 * 8) - 512;
            float4 v0 = make_float4(0.f, 0.f, 0.f, 0.f);
            float4 v1 = make_float4(0.f, 0.f, 0.f, 0.f);
            if (t1abs < T1_LEN && g >= 0) {
                v0 = *(const float4*)(xb + g);
                v1 = *(const float4*)(xb + g + 4);
            }
            float fv[8] = {v0.x, v0.y, v0.z, v0.w, v1.x, v1.y, v1.z, v1.w};
            unsigned hp[4], lp[4];
            #pragma unroll
            for (int e = 0; e < 4; ++e) {
                unsigned h0 = bf16_rne(fv[2 * e]);
                unsigned l0 = bf16_rne(fv[2 * e]     - __uint_as_float(h0 << 16));
                unsigned h1 = bf16_rne(fv[2 * e + 1]);
                unsigned l1 = bf16_rne(fv[2 * e + 1] - __uint_as_float(h1 << 16));
                hp[e] = h0 | (h1 << 16);
                lp[e] = l0 | (l1 << 16);
            }
            int dst = row * 64 + ((c8 ^ (row & 7)) << 3);
            *(int4*)(Bhi + dst) = make_int4(hp[0], hp[1], hp[2], hp[3]);
            *(int4*)(Blo + dst) = make_int4(lp[0], lp[1], lp[2], lp[3]);
        }
        __syncthreads();

        #pragma unroll
        for (int ks = 0; ks < 2; ++ks) {
            const int ch = ks * 4 + quad;
            bf16x8 ah[4], al[4], bh[3], bl[3];
            #pragma unroll
            for (int mi = 0; mi < 4; ++mi) {
                int o = offA[mi] + ((ch ^ swA[mi]) << 3);
                ah[mi] = *(const bf16x8*)(Ahi + o);
                al[mi] = *(const bf16x8*)(Alo + o);
            }
            #pragma unroll
            for (int ni = 0; ni < 3; ++ni) {
                int o = offB[ni] + ((ch ^ swB[ni]) << 3);
                bh[ni] = *(const bf16x8*)(Bhi + o);
                bl[ni] = *(const bf16x8*)(Blo + o);
            }
            #pragma unroll
            for (int mi = 0; mi < 4; ++mi)
                #pragma unroll
                for (int ni = 0; ni < 3; ++ni) {
                    acc[mi][ni] = __builtin_amdgcn_mfma_f32_16x16x32_bf16(ah[mi], bh[ni], acc[mi][ni], 0, 0, 0);
                    acc[mi][ni] = __builtin_amdgcn_mfma_f32_16x16x32_bf16(ah[mi], bl[ni], acc[mi][ni], 0, 0, 0);
                    acc[mi][ni] = __builtin_amdgcn_mfma_f32_16x16x32_bf16(al[mi], bh[ni], acc[mi][ni], 0, 0, 0);
                }
        }
        __syncthreads();
    }

    // ---- epilogue: bias + pair-maxpool (adjacent regs) + mod-3 w2 weighting
    // est contribution: sum_t2 s[b,t2] = 228*b2 + sum over (j,t1) of
    // hm[j,t1] * w2[j][(t1+1)%3]
    float contrib = 0.f;
    #pragma unroll
    for (int mi = 0; mi < 4; ++mi) {
        const int cbase = c0w + mi * 16 + (quad << 2);   // D row = quad*4 + reg
        const float bb0 = b1s[cbase], bb1 = b1s[cbase + 1];
        const float bb2 = b1s[cbase + 2], bb3 = b1s[cbase + 3];
        const int j0 = cbase >> 1;
        #pragma unroll
        for (int ni = 0; ni < 3; ++ni) {
            const int t1 = t1g0 + t0w + ni * 16 + l15;   // D col = lane&15
            if (t1 < T1_LEN) {
                float p0 = fmaxf(acc[mi][ni][0] + bb0, acc[mi][ni][1] + bb1);
                float p1 = fmaxf(acc[mi][ni][2] + bb2, acc[mi][ni][3] + bb3);
                int r = (t1 + 1) % 3;
                contrib += p0 * w2s[j0 * 3 + r] + p1 * w2s[(j0 + 1) * 3 + r];
            }
        }
    }
    red[tid] = contrib;
    __syncthreads();
    for (int off = 128; off > 0; off >>= 1) {
        if (tid < off) red[tid] += red[tid + off];
        __syncthreads();
    }
    if (tid == 0) atomicAdd(est_raw + b, red[0]);
}

// ---------------------------------------------------------------------------
// Top-32 of 64 (ties -> lower index), ascending compaction; writes sel idx
// and sel_lens (as float, tail of d_out).
__global__ void select_k(const float* __restrict__ est_raw,
                         const float* __restrict__ b2,
                         const int* __restrict__ seq_lens,
                         int* __restrict__ sel,
                         float* __restrict__ out_lens) {
    const int i = threadIdx.x;   // 64 threads = 1 wave
    __shared__ float e[64];
    const int L  = seq_lens[i];
    const int sl = ((L + 2) / 3 + 2) / 3;
    const float ei = (est_raw[i] + 228.0f * b2[0]) / (float)sl;  // = sum/sl
    e[i] = ei;
    __syncthreads();
    int rank = 0;
    for (int j = 0; j < 64; ++j) {
        float ej = e[j];
        rank += (ej > ei) || (ej == ei && j < i);
    }
    const bool selq = rank < NSEL;
    const unsigned long long m = __ballot(selq);
    if (selq) {
        int pos = __popcll(m & ((1ull << i) - 1ull));
        sel[pos] = i;
        out_lens[pos] = (float)L;
    }
}

// ---------------------------------------------------------------------------
__global__ __launch_bounds__(256) void gather_rows(const float* __restrict__ x,
                                                   const int* __restrict__ sel,
                                                   float* __restrict__ out,
                                                   int n4row) {
    const int i = blockIdx.y;
    const int v = blockIdx.x * 256 + threadIdx.x;
    if (v < n4row) {
        const int src = sel[i];
        const float4* xs = (const float4*)(x + (size_t)src * T_LEN * D_DIM);
        float4* od = (float4*)(out + (size_t)i * ((size_t)n4row * 4));
        od[v] = xs[v];
    }
}

// ---------------------------------------------------------------------------
extern "C" void kernel_launch(void* const* d_in, const int* in_sizes, int n_in,
                              void* d_out, int out_size, void* d_ws, size_t ws_size,
                              hipStream_t stream) {
    const float* x        = (const float*)d_in[0];
    const int*   seq_lens = (const int*)  d_in[1];
    const float* w1       = (const float*)d_in[2];
    const float* b1       = (const float*)d_in[3];
    const float* w2       = (const float*)d_in[4];
    const float* b2       = (const float*)d_in[5];
    float* out = (float*)d_out;

    char* ws = (char*)d_ws;
    unsigned short* whi = (unsigned short*)(ws + OFF_WHI);
    unsigned short* wlo = (unsigned short*)(ws + OFF_WLO);
    float* est_raw = (float*)(ws + OFF_EST);
    int*   sel     = (int*)  (ws + OFF_SEL);

    const int max_time = (out_size - NSEL) / (NSEL * D_DIM);

    pack_w1_split<<<768, 256, 0, stream>>>(w1, whi, wlo, est_raw);
    conv1_mfma<<<dim3(NTILES, B_SZ), 256, 0, stream>>>(x, whi, wlo, b1, w2, est_raw);
    select_k<<<1, 64, 0, stream>>>(est_raw, b2, seq_lens, sel,
                                   out + (size_t)NSEL * max_time * D_DIM);
    const int n4row = max_time * (D_DIM / 4);
    gather_rows<<<dim3((n4row + 255) / 256, NSEL), 256, 0, stream>>>(x, sel, out, n4row);
}